// Round 2
// baseline (425.945 us; speedup 1.0000x reference)
//
#include <hip/hip_runtime.h>

// Reference = patchify ∘ depatchify = identity. Output is bit-identical to
// the input, so the optimal kernel is a pure D2D copy of 256 MiB.
//
// R1 measured: harness reset fills run at 6.3-6.5 TB/s; our float4 copy
// didn't make the rocprof top-5 (< 163 us), so dur_us=421 is dominated by
// harness reset traffic. This round: use the runtime's tuned blit path
// (hipMemcpyAsync d2d, graph-capture-safe) to test whether the copy itself
// has any headroom left.

extern "C" void kernel_launch(void* const* d_in, const int* in_sizes, int n_in,
                              void* d_out, int out_size, void* d_ws, size_t ws_size,
                              hipStream_t stream) {
    const void* images = d_in[0];
    size_t bytes = (size_t)out_size * sizeof(float);   // 64*1*1024*1024*4 = 256 MiB
    hipMemcpyAsync(d_out, images, bytes, hipMemcpyDeviceToDevice, stream);
}